// Round 1
// baseline (5304.848 us; speedup 1.0000x reference)
//
#include <hip/hip_runtime.h>

// ---------------------------------------------------------------------------
// RoadNetworkEncoder: 2x GATv2 (road graph) + 2x GCN (zone graph), f32, H=128
// ---------------------------------------------------------------------------

__global__ __launch_bounds__(256) void feat_kernel(
    const float* __restrict__ id_emb, const float* __restrict__ lenW, const float* __restrict__ lenb,
    const float* __restrict__ type_emb, const float* __restrict__ lonW, const float* __restrict__ lonb,
    const float* __restrict__ latW, const float* __restrict__ latb,
    const float* __restrict__ alen, const int* __restrict__ atype,
    const float* __restrict__ alon, const float* __restrict__ alat,
    float* __restrict__ x, int N) {
  int idx = blockIdx.x * 256 + threadIdx.x;
  if (idx >= N * 128) return;
  int node = idx >> 7, j = idx & 127;
  float v;
  if (j < 64) v = id_emb[(node << 6) + j];
  else if (j < 80) v = alen[node] * lenW[j - 64] + lenb[j - 64];
  else if (j < 96) v = type_emb[atype[node] * 16 + (j - 80)];
  else if (j < 112) v = alon[node] * lonW[j - 96] + lonb[j - 96];
  else v = alat[node] * latW[j - 112] + latb[j - 112];
  x[idx] = v;
}

__global__ __launch_bounds__(256) void ea_accum(const int* __restrict__ dst, const float* __restrict__ ia,
                                                float* __restrict__ easum, float* __restrict__ cnt, int E) {
  int e = blockIdx.x * 256 + threadIdx.x;
  if (e >= E) return;
  int d = dst[e];
  atomicAdd(cnt + d, 1.0f);
  atomicAdd(easum + 2 * d, ia[2 * e]);
  atomicAdd(easum + 2 * d + 1, ia[2 * e + 1]);
}

__global__ __launch_bounds__(256) void ea_final(float* __restrict__ easum, const float* __restrict__ cnt, int N) {
  int i = blockIdx.x * 256 + threadIdx.x;
  if (i >= N) return;
  float c = fmaxf(cnt[i], 1.0f);
  easum[2 * i] /= c;
  easum[2 * i + 1] /= c;
}

// Y[N,128] = X[N,128] @ W[128,128] (+bias) (relu). Block: 64 rows x 64 cols.
__global__ __launch_bounds__(256) void gemm128(const float* __restrict__ X, const float* __restrict__ W,
                                               const float* __restrict__ bias, float* __restrict__ Y,
                                               int N, int relu) {
  __shared__ float Ws[128 * 64];
  __shared__ float Xs[64 * 128];
  int row0 = (blockIdx.x >> 1) * 64;
  int col0 = (blockIdx.x & 1) * 64;
  int t = threadIdx.x;
  for (int i = t; i < 2048; i += 256) {
    int k = i >> 4, j4 = i & 15;
    *reinterpret_cast<float4*>(Ws + k * 64 + j4 * 4) =
        *reinterpret_cast<const float4*>(W + k * 128 + col0 + j4 * 4);
  }
  for (int i = t; i < 2048; i += 256) {
    int r = i >> 5, k4 = i & 31;
    int row = row0 + r;
    float4 xv = make_float4(0.f, 0.f, 0.f, 0.f);
    if (row < N) xv = *reinterpret_cast<const float4*>(X + row * 128 + k4 * 4);
    *reinterpret_cast<float4*>(Xs + r * 128 + k4 * 4) = xv;
  }
  __syncthreads();
  int c = t & 15, g = t >> 4;
  float acc[4][4] = {{0.f}};
  for (int k = 0; k < 128; ++k) {
    float4 w = *reinterpret_cast<const float4*>(Ws + k * 64 + c * 4);
    float x0 = Xs[(g * 4 + 0) * 128 + k];
    float x1 = Xs[(g * 4 + 1) * 128 + k];
    float x2 = Xs[(g * 4 + 2) * 128 + k];
    float x3 = Xs[(g * 4 + 3) * 128 + k];
    acc[0][0] += x0 * w.x; acc[0][1] += x0 * w.y; acc[0][2] += x0 * w.z; acc[0][3] += x0 * w.w;
    acc[1][0] += x1 * w.x; acc[1][1] += x1 * w.y; acc[1][2] += x1 * w.z; acc[1][3] += x1 * w.w;
    acc[2][0] += x2 * w.x; acc[2][1] += x2 * w.y; acc[2][2] += x2 * w.z; acc[2][3] += x2 * w.w;
    acc[3][0] += x3 * w.x; acc[3][1] += x3 * w.y; acc[3][2] += x3 * w.z; acc[3][3] += x3 * w.w;
  }
  float4 bv = make_float4(0.f, 0.f, 0.f, 0.f);
  if (bias) bv = *reinterpret_cast<const float4*>(bias + col0 + c * 4);
  for (int i = 0; i < 4; ++i) {
    int row = row0 + g * 4 + i;
    if (row >= N) continue;
    float4 o;
    o.x = acc[i][0] + bv.x;
    o.y = acc[i][1] + bv.y;
    o.z = acc[i][2] + bv.z;
    o.w = acc[i][3] + bv.w;
    if (relu) {
      o.x = fmaxf(o.x, 0.f); o.y = fmaxf(o.y, 0.f);
      o.z = fmaxf(o.z, 0.f); o.w = fmaxf(o.w, 0.f);
    }
    *reinterpret_cast<float4*>(Y + row * 128 + col0 + c * 4) = o;
  }
}

// logits: one 16-lane group per edge (incl. self-loops e >= E)
__global__ __launch_bounds__(256) void gat_logits(
    const float* __restrict__ xl, const float* __restrict__ xr,
    const int* __restrict__ src, const int* __restrict__ dst,
    const float* __restrict__ ia, const float* __restrict__ mean_ea,
    const float* __restrict__ We, const float* __restrict__ att,
    float* __restrict__ logit, unsigned int* __restrict__ mkey, int E, int N) {
  int e = blockIdx.x * 16 + (threadIdx.x >> 4);
  int lane = threadIdx.x & 15;
  if (e >= E + N) return;
  int s, d;
  float ea0, ea1;
  if (e < E) {
    s = src[e]; d = dst[e]; ea0 = ia[2 * e]; ea1 = ia[2 * e + 1];
  } else {
    s = d = e - E; ea0 = mean_ea[2 * s]; ea1 = mean_ea[2 * s + 1];
  }
  const float4* XL = reinterpret_cast<const float4*>(xl + (size_t)s * 128);
  const float4* XR = reinterpret_cast<const float4*>(xr + (size_t)d * 128);
  const float4* W0 = reinterpret_cast<const float4*>(We);
  const float4* W1 = reinterpret_cast<const float4*>(We + 128);
  const float4* AT = reinterpret_cast<const float4*>(att);
  float acc = 0.f;
  for (int q = 0; q < 2; ++q) {
    int h4 = lane * 2 + q;
    float4 a = XL[h4], b = XR[h4], w0 = W0[h4], w1 = W1[h4], at = AT[h4];
    float v;
    v = a.x + b.x + ea0 * w0.x + ea1 * w1.x; v = v > 0.f ? v : 0.2f * v; acc += v * at.x;
    v = a.y + b.y + ea0 * w0.y + ea1 * w1.y; v = v > 0.f ? v : 0.2f * v; acc += v * at.y;
    v = a.z + b.z + ea0 * w0.z + ea1 * w1.z; v = v > 0.f ? v : 0.2f * v; acc += v * at.z;
    v = a.w + b.w + ea0 * w0.w + ea1 * w1.w; v = v > 0.f ? v : 0.2f * v; acc += v * at.w;
  }
  for (int off = 8; off; off >>= 1) acc += __shfl_xor(acc, off);
  if (lane == 0) {
    logit[e] = acc;
    unsigned int u = __float_as_uint(acc);
    unsigned int key = (u & 0x80000000u) ? ~u : (u | 0x80000000u);
    atomicMax(mkey + d, key);
  }
}

__global__ __launch_bounds__(256) void gat_soft(float* __restrict__ lg, const int* __restrict__ dst,
                                                const unsigned int* __restrict__ mkey,
                                                float* __restrict__ denom, int E, int N) {
  int e = blockIdx.x * 256 + threadIdx.x;
  if (e >= E + N) return;
  int d = (e < E) ? dst[e] : (e - E);
  unsigned int key = mkey[d];
  unsigned int u = (key & 0x80000000u) ? (key & 0x7fffffffu) : ~key;
  float m = __uint_as_float(u);
  float ex = expf(lg[e] - m);
  lg[e] = ex;
  atomicAdd(denom + d, ex);
}

__global__ __launch_bounds__(256) void gat_aggr(const float* __restrict__ xl, const float* __restrict__ ex,
                                                const float* __restrict__ denom,
                                                const int* __restrict__ src, const int* __restrict__ dst,
                                                float* __restrict__ out, int E, int N) {
  int e = blockIdx.x * 16 + (threadIdx.x >> 4);
  int lane = threadIdx.x & 15;
  if (e >= E + N) return;
  int s, d;
  if (e < E) { s = src[e]; d = dst[e]; } else { s = d = e - E; }
  float alpha = ex[e] / denom[d];
  const float4* XL = reinterpret_cast<const float4*>(xl + (size_t)s * 128);
  for (int q = 0; q < 2; ++q) {
    int h4 = lane * 2 + q;
    float4 a = XL[h4];
    float* o = out + (size_t)d * 128 + h4 * 4;
    atomicAdd(o + 0, alpha * a.x);
    atomicAdd(o + 1, alpha * a.y);
    atomicAdd(o + 2, alpha * a.z);
    atomicAdd(o + 3, alpha * a.w);
  }
}

__global__ __launch_bounds__(256) void bias_act(float* __restrict__ y, const float* __restrict__ b,
                                                int N, int relu) {
  int i = blockIdx.x * 256 + threadIdx.x;
  if (i >= N * 128) return;
  float v = y[i] + b[i & 127];
  if (relu) v = fmaxf(v, 0.f);
  y[i] = v;
}

__global__ __launch_bounds__(256) void deg_accum(const int* __restrict__ dst, const float* __restrict__ w,
                                                 float* __restrict__ deg, int E) {
  int e = blockIdx.x * 256 + threadIdx.x;
  if (e >= E) return;
  atomicAdd(deg + dst[e], w[e]);
}

__global__ __launch_bounds__(256) void dinv_kernel(float* __restrict__ deg, int N) {
  int i = blockIdx.x * 256 + threadIdx.x;
  if (i >= N) return;
  deg[i] = rsqrtf(deg[i] + 1.0f);  // +1 self-loop weight; deg >= 1 > 0
}

__global__ __launch_bounds__(256) void gcn_edge(const float* __restrict__ h, const float* __restrict__ dinv,
                                                const int* __restrict__ src, const int* __restrict__ dst,
                                                const float* __restrict__ w, float* __restrict__ out, int E) {
  int e = blockIdx.x * 16 + (threadIdx.x >> 4);
  int lane = threadIdx.x & 15;
  if (e >= E) return;
  int s = src[e], d = dst[e];
  float coef = dinv[s] * w[e] * dinv[d];
  const float4* H = reinterpret_cast<const float4*>(h + (size_t)s * 128);
  for (int q = 0; q < 2; ++q) {
    int h4 = lane * 2 + q;
    float4 a = H[h4];
    float* o = out + (size_t)d * 128 + h4 * 4;
    atomicAdd(o + 0, coef * a.x);
    atomicAdd(o + 1, coef * a.y);
    atomicAdd(o + 2, coef * a.z);
    atomicAdd(o + 3, coef * a.w);
  }
}

__global__ __launch_bounds__(256) void gcn_epi(float* __restrict__ out, const float* __restrict__ h,
                                               const float* __restrict__ dinv, const float* __restrict__ b,
                                               int N, int relu) {
  int i = blockIdx.x * 256 + threadIdx.x;
  if (i >= N * 128) return;
  int node = i >> 7, j = i & 127;
  float dv = dinv[node];
  float v = out[i] + dv * dv * h[i] + b[j];
  if (relu) v = fmaxf(v, 0.f);
  out[i] = v;
}

extern "C" void kernel_launch(void* const* d_in, const int* in_sizes, int n_in,
                              void* d_out, int out_size, void* d_ws, size_t ws_size,
                              hipStream_t stream) {
  const float* road_id_emb = (const float*)d_in[0];
  const float* len_W = (const float*)d_in[1];
  const float* len_b = (const float*)d_in[2];
  const float* type_emb = (const float*)d_in[3];
  const float* lon_W = (const float*)d_in[4];
  const float* lon_b = (const float*)d_in[5];
  const float* lat_W = (const float*)d_in[6];
  const float* lat_b = (const float*)d_in[7];
  const float* alen = (const float*)d_in[8];
  const int* atype = (const int*)d_in[9];
  const float* alon = (const float*)d_in[10];
  const float* alat = (const float*)d_in[11];
  const int* rei = (const int*)d_in[12];
  const float* ia = (const float*)d_in[13];
  const float* zone_emb = (const float*)d_in[28];
  const int* zei = (const int*)d_in[29];
  const float* zw = (const float*)d_in[30];
  const float* gcn1_W = (const float*)d_in[31];
  const float* gcn1_b = (const float*)d_in[32];
  const float* gcn2_W = (const float*)d_in[33];
  const float* gcn2_b = (const float*)d_in[34];

  const int N = in_sizes[8];          // 100000
  const int E = in_sizes[12] / 2;     // 400000
  const int NZ = in_sizes[28] / 128;  // 20000
  const int EZ = in_sizes[30];        // 160000
  const int E2 = E + N;

  const int* src = rei;
  const int* dst = rei + E;
  const int* zsrc = zei;
  const int* zdst = zei + EZ;

  float* ws = (float*)d_ws;
  float* A = ws;
  float* B = A + (size_t)N * 128;
  float* C = B + (size_t)N * 128;
  float* easum = C + (size_t)N * 128;       // 2N, becomes mean_ea
  float* cnt = easum + 2 * (size_t)N;       // N
  float* logit = cnt + N;                   // E2 (becomes ex in-place)
  float* denom = logit + E2;                // N
  unsigned int* mkey = (unsigned int*)(denom + N);  // N
  float* deg = (float*)(mkey + N);          // NZ

  float* road_out = (float*)d_out;
  float* zone_out = road_out + (size_t)N * 128;

  // ---- road node features ----
  feat_kernel<<<(N * 128 + 255) / 256, 256, 0, stream>>>(
      road_id_emb, len_W, len_b, type_emb, lon_W, lon_b, lat_W, lat_b,
      alen, atype, alon, alat, A, N);

  // ---- mean edge attr per dst (self-loop fill) ----
  hipMemsetAsync(easum, 0, 3 * (size_t)N * sizeof(float), stream);  // easum + cnt
  ea_accum<<<(E + 255) / 256, 256, 0, stream>>>(dst, ia, easum, cnt, E);
  ea_final<<<(N + 255) / 256, 256, 0, stream>>>(easum, cnt, N);

  const int gemm_grid = ((N + 63) / 64) * 2;

  auto gat = [&](const float* xin, int base, float* xl, float* xr, float* outp, int relu) {
    const float* Wl = (const float*)d_in[base + 0];
    const float* bl = (const float*)d_in[base + 1];
    const float* Wr = (const float*)d_in[base + 2];
    const float* br = (const float*)d_in[base + 3];
    const float* We = (const float*)d_in[base + 4];
    const float* att = (const float*)d_in[base + 5];
    const float* bias = (const float*)d_in[base + 6];
    gemm128<<<gemm_grid, 256, 0, stream>>>(xin, Wl, bl, xl, N, 0);
    gemm128<<<gemm_grid, 256, 0, stream>>>(xin, Wr, br, xr, N, 0);
    hipMemsetAsync(denom, 0, 2 * (size_t)N * sizeof(float), stream);  // denom + mkey
    gat_logits<<<(E2 + 15) / 16, 256, 0, stream>>>(xl, xr, src, dst, ia, easum, We, att, logit, mkey, E, N);
    gat_soft<<<(E2 + 255) / 256, 256, 0, stream>>>(logit, dst, mkey, denom, E, N);
    hipMemsetAsync(outp, 0, (size_t)N * 128 * sizeof(float), stream);
    gat_aggr<<<(E2 + 15) / 16, 256, 0, stream>>>(xl, logit, denom, src, dst, outp, E, N);
    bias_act<<<(N * 128 + 255) / 256, 256, 0, stream>>>(outp, bias, N, relu);
  };

  // layer 1: x=A, xl=C, xr=B, out=B (xr dead after logits), relu
  gat(A, 14, C, B, B, 1);
  // layer 2: x=B, xl=C, xr=A, out=d_out road region, no relu
  gat(B, 21, C, A, road_out, 0);

  // ---- zone GCN (buffers alias A; road pipeline complete by stream order) ----
  float* HG = A;                       // NZ*128
  float* ZA = A + (size_t)NZ * 128;    // NZ*128

  hipMemsetAsync(deg, 0, (size_t)NZ * sizeof(float), stream);
  deg_accum<<<(EZ + 255) / 256, 256, 0, stream>>>(zdst, zw, deg, EZ);
  dinv_kernel<<<(NZ + 255) / 256, 256, 0, stream>>>(deg, NZ);

  const int zgrid = ((NZ + 63) / 64) * 2;
  // layer 1
  gemm128<<<zgrid, 256, 0, stream>>>(zone_emb, gcn1_W, nullptr, HG, NZ, 0);
  hipMemsetAsync(ZA, 0, (size_t)NZ * 128 * sizeof(float), stream);
  gcn_edge<<<(EZ + 15) / 16, 256, 0, stream>>>(HG, deg, zsrc, zdst, zw, ZA, EZ);
  gcn_epi<<<(NZ * 128 + 255) / 256, 256, 0, stream>>>(ZA, HG, deg, gcn1_b, NZ, 1);
  // layer 2
  gemm128<<<zgrid, 256, 0, stream>>>(ZA, gcn2_W, nullptr, HG, NZ, 0);
  hipMemsetAsync(zone_out, 0, (size_t)NZ * 128 * sizeof(float), stream);
  gcn_edge<<<(EZ + 15) / 16, 256, 0, stream>>>(HG, deg, zsrc, zdst, zw, zone_out, EZ);
  gcn_epi<<<(NZ * 128 + 255) / 256, 256, 0, stream>>>(zone_out, HG, deg, gcn2_b, NZ, 0);
}